// Round 17
// baseline (1694.868 us; speedup 1.0000x reference)
//
#include <hip/hip_runtime.h>
#include <hip/hip_bf16.h>

#define Tn 4096
#define Dm 2048
#define En 8
#define Hh 5461
#define HP 5504   // 43 * 128 = 86 * 64

typedef __attribute__((ext_vector_type(8))) short bf16x8;
typedef __attribute__((ext_vector_type(4))) float f32x4;

__device__ __forceinline__ unsigned short f2bf(float f) {
  union { __hip_bfloat16 b; unsigned short u; } c;
  c.b = __float2bfloat16(f);
  return c.u;
}

__device__ __forceinline__ uint4 pack8(const float* f) {
  union { unsigned short us[8]; uint4 v; } o;
#pragma unroll
  for (int i = 0; i < 8; ++i) o.us[i] = f2bf(f[i]);
  return o.v;
}

// async 16B global -> LDS. lds must be wave-uniform; HW adds lane*16.
__device__ __forceinline__ void gl16(const void* g, void* lds) {
  __builtin_amdgcn_global_load_lds(
      (const __attribute__((address_space(1))) unsigned int*)g,
      (__attribute__((address_space(3))) unsigned int*)lds, 16, 0, 0);
}

// FUSED counted-wait + barrier. Single asm block.
#define WAIT8_BAR() asm volatile("s_waitcnt vmcnt(8)\n\ts_barrier" ::: "memory")
#define WAIT6_BAR() asm volatile("s_waitcnt vmcnt(6)\n\ts_barrier" ::: "memory")
#define WAIT4_BAR() asm volatile("s_waitcnt vmcnt(4)\n\ts_barrier" ::: "memory")
#define WAIT0_BAR() asm volatile("s_waitcnt vmcnt(0)\n\ts_barrier" ::: "memory")
// Trailing barrier (2-phase kernels): drain own LDS reads then barrier.
#define LGK0_BAR()  asm volatile("s_waitcnt lgkmcnt(0)\n\ts_barrier" ::: "memory")
// Per-phase (8-wave gemm1): barrier then drain own ds_reads; plain barrier.
#define BAR_LGK0()  asm volatile("s_barrier\n\ts_waitcnt lgkmcnt(0)" ::: "memory")
#define BARP()      asm volatile("s_barrier" ::: "memory")

// LDS 16B-unit XOR swizzle (verified r8/9: SQ_LDS_BANK_CONFLICT -> 0):
// global unit (row,q) -> LDS unit row*4 + (q ^ ((row>>1)&3)).

// ---------------- gating: logits + probs + top-2 + fused x->bf16 ----------------
__global__ __launch_bounds__(64) void gating_kernel(
    const float* __restrict__ x, const float* __restrict__ wg,
    float* __restrict__ gate_p, int* __restrict__ topk_e, float* __restrict__ topk_p,
    unsigned short* __restrict__ xb)
{
  const int t = blockIdx.x;
  const int l = threadIdx.x;
  const float* xr = x + (size_t)t * Dm;
  float acc[En];
#pragma unroll
  for (int e = 0; e < En; ++e) acc[e] = 0.f;
  for (int d = l; d < Dm; d += 64) {
    const float xv = xr[d];
#pragma unroll
    for (int e = 0; e < En; ++e) acc[e] = fmaf(xv, wg[e * Dm + d], acc[e]);
  }
#pragma unroll
  for (int e = 0; e < En; ++e) {
    float v = acc[e];
#pragma unroll
    for (int s = 32; s > 0; s >>= 1) v += __shfl_xor(v, s);
    acc[e] = v;
  }
  unsigned short* xrow = xb + (size_t)t * Dm;
#pragma unroll
  for (int k = 0; k < 4; ++k) {
    const int b = k * 512 + l * 8;
    float f[8];
    *(float4*)(f)     = *(const float4*)(xr + b);
    *(float4*)(f + 4) = *(const float4*)(xr + b + 4);
    *(uint4*)(xrow + b) = pack8(f);
  }
  if (l == 0) {
    float m = acc[0];
    for (int e = 1; e < En; ++e) m = fmaxf(m, acc[e]);
    float p[En]; float s = 0.f;
    for (int e = 0; e < En; ++e) { p[e] = __expf(acc[e] - m); s += p[e]; }
    const float inv = 1.f / s;
    for (int e = 0; e < En; ++e) gate_p[t * En + e] = p[e] * inv;
    int e0 = 0; float v0 = acc[0];
    for (int e = 1; e < En; ++e) if (acc[e] > v0) { v0 = acc[e]; e0 = e; }
    int e1 = -1; float v1 = -3.4e38f;
    for (int e = 0; e < En; ++e) if (e != e0 && acc[e] > v1) { v1 = acc[e]; e1 = e; }
    const float q  = __expf(v1 - v0);
    const float q0 = 1.f / (1.f + q);
    const float q1 = q * q0;
    topk_e[t * 2] = e0; topk_e[t * 2 + 1] = e1;
    topk_p[t * 2] = q0; topk_p[t * 2 + 1] = q1;
  }
}

// ---------------- reduce+scatter (single block, LDS atomics only) ----------------
__global__ __launch_bounds__(256) void reduce_scatter_kernel(
    const int* __restrict__ topk_e, const float* __restrict__ topk_p,
    const float* __restrict__ gate_p,
    int* __restrict__ counts, int* __restrict__ offs,
    int* __restrict__ pair_token, int* __restrict__ slot_of,
    float* __restrict__ out_scalar)
{
  __shared__ int cnt_s[En];
  __shared__ int run_s[En];
  __shared__ float red[256 * En];
  const int tid = threadIdx.x;
  if (tid < En) cnt_s[tid] = 0;
  __syncthreads();
  for (int i = tid; i < Tn * 2; i += 256) atomicAdd(&cnt_s[topk_e[i]], 1);
  __syncthreads();
  if (tid == 0) {
    int o = 0;
    for (int e = 0; e < En; ++e) {
      offs[e] = o; run_s[e] = o; counts[e] = cnt_s[e]; o += cnt_s[e];
    }
  }
  __syncthreads();
  for (int i = tid; i < Tn * 2; i += 256) {
    const int e = topk_e[i];
    const int slot = atomicAdd(&run_s[e], 1);
    pair_token[slot] = i >> 1;
    slot_of[i] = slot;
  }
  float p8[En];
#pragma unroll
  for (int e = 0; e < En; ++e) p8[e] = 0.f;
  for (int t = tid; t < Tn; t += 256)
#pragma unroll
    for (int e = 0; e < En; ++e) p8[e] += gate_p[t * En + e];
#pragma unroll
  for (int e = 0; e < En; ++e) red[tid * En + e] = p8[e];
  __syncthreads();
  for (int s = 128; s > 0; s >>= 1) {
    if (tid < s)
#pragma unroll
      for (int e = 0; e < En; ++e) red[tid * En + e] += red[(tid + s) * En + e];
    __syncthreads();
  }
  if (tid == 0) {
    double mp[En]; double sum = 0.0;
    for (int e = 0; e < En; ++e) { mp[e] = (double)red[e] / (double)Tn; sum += mp[e]; }
    const double mean = sum / En;
    double var = 0.0;
    for (int e = 0; e < En; ++e) { const double d = mp[e] - mean; var += d * d; }
    var /= (En - 1);
    const double denom = mean + 1e-10;
    *out_scalar = (float)(0.01 * var / (denom * denom));
  }
}

// ---------------- w1/w3 fp32 [E][Hh][Dm] -> bf16 [E][HP][Dm], pad rows zero ----------------
__global__ __launch_bounds__(256) void cvt_w13_kernel(
    const float* __restrict__ w1, const float* __restrict__ w3,
    unsigned short* __restrict__ w1b, unsigned short* __restrict__ w3b)
{
  const float* src = blockIdx.y ? w3 : w1;
  unsigned short* dst = blockIdx.y ? w3b : w1b;
  const unsigned i = ((unsigned)blockIdx.x * 256u + threadIdx.x) * 8u;
  const unsigned per_e = (unsigned)HP * Dm;
  const unsigned e = i / per_e;
  const unsigned r = i % per_e;
  const unsigned row = r / Dm, col = r % Dm;
  uint4 v;
  if (row < Hh) {
    const float* s = src + (size_t)e * Hh * Dm + (size_t)row * Dm + col;
    float f[8];
    *(float4*)(f)     = *(const float4*)(s);
    *(float4*)(f + 4) = *(const float4*)(s + 4);
    v = pack8(f);
  } else {
    v = (uint4){0, 0, 0, 0};
  }
  *(uint4*)(dst + i) = v;
}

// ---------------- w2 fp32 [E][Dm][Hh] -> bf16 [E][Dm][HP], pad cols zero ----------------
__global__ __launch_bounds__(256) void cvt_w2_kernel(const float* __restrict__ w2,
                                                     unsigned short* __restrict__ w2b)
{
  const unsigned i = ((unsigned)blockIdx.x * 256u + threadIdx.x) * 8u;
  const unsigned per_e = (unsigned)Dm * HP;
  const unsigned e = i / per_e;
  const unsigned r = i % per_e;
  const unsigned row = r / HP, col = r % HP;
  const float* s = w2 + (size_t)e * Dm * Hh + (size_t)row * Hh + col;
  float f[8];
#pragma unroll
  for (int k = 0; k < 8; ++k) f[k] = (col + k < Hh) ? s[k] : 0.f;
  *(uint4*)(w2b + i) = pack8(f);
}

// ---------------- GEMM1: h = silu(x w1^T) * (x w3^T), routed ----------------
// NEW: 256x128 tile, 512 thr = 8 waves (4m x 2n), BK=32, 3-buffer ring with
// counted vmcnt(8) once per K-step, 4 barrier-phases x 8 MFMA, setprio, swizzle.
__global__ __launch_bounds__(512, 2) void gemm1_kernel(
    const unsigned short* __restrict__ xb,
    const unsigned short* __restrict__ w1b, const unsigned short* __restrict__ w3b,
    const int* __restrict__ counts, const int* __restrict__ offs,
    const int* __restrict__ pair_token,
    unsigned short* __restrict__ h)
{
  // nwg = 43*8*4 = 1376; chunk = 172 (bijective XCD remap)
  const int bid = blockIdx.x;
  const int logical = (bid & 7) * 172 + (bid >> 3);
  const int z  = logical & 3;
  const int pe = logical >> 2;
  const int e  = pe & 7;
  const int jp = pe >> 3;

  const int cnt = counts[e];
  if (cnt <= 0) return;
  const int base = offs[e];
  const int j0 = jp * 128;
  const int tid = threadIdx.x;
  const int l = tid & 63;
  const int wid = tid >> 6;     // 0..7
  const int wr = wid & 3;       // m-group: 4 x 64 rows
  const int wc = wid >> 2;      // n-group: 2 x 64 cols

  __shared__ unsigned short As[3][256 * 32];   // 16 KB each
  __shared__ unsigned short B1s[3][128 * 32];  // 8 KB each
  __shared__ unsigned short B3s[3][128 * 32];  // 8 KB each  -> total 96 KB

  // staging: unit u -> LDS linear; global source col swizzled.
  // A: 2 units/thread (u=tid -> rows 0..127, u=512+tid -> rows 128..255).
  // B1/B3: 1 unit/thread (u=tid -> rows 0..127).
  const int r0 = tid >> 2;                               // 0..127
  const int c0 = (((tid & 3) ^ ((tid >> 3) & 3))) * 8;   // swizzled col8 (both A halves + B)
  const int wbA0 = wid * 512;          // wave-uniform LDS elem bases
  const int wbA1 = 4096 + wid * 512;
  const int wbB  = wid * 512;

  const unsigned short* b1g = w1b + ((size_t)e * HP + j0 + r0) * Dm + c0;
  const unsigned short* b3g = w3b + ((size_t)e * HP + j0 + r0) * Dm + c0;

  const int lr = l & 15;
  const int sq = (((l >> 4) ^ ((lr >> 1) & 3))) * 8;

#define STG(b, kk) do { \
    gl16(a0g + (kk), &As[b][wbA0]); gl16(a1g + (kk), &As[b][wbA1]); \
    gl16(b1g + (kk), &B1s[b][wbB]); gl16(b3g + (kk), &B3s[b][wbB]); \
  } while (0)

// 4 phases: {acc1 n0-1} {acc3 n0-1} {acc1 n2-3} {acc3 n2-3}; A read once, held.
#define PHASES(b) do { \
    bf16x8 av0 = *(const bf16x8*)(&As[b][(wr * 64 +  0 + lr) * 32 + sq]); \
    bf16x8 av1 = *(const bf16x8*)(&As[b][(wr * 64 + 16 + lr) * 32 + sq]); \
    bf16x8 av2 = *(const bf16x8*)(&As[b][(wr * 64 + 32 + lr) * 32 + sq]); \
    bf16x8 av3 = *(const bf16x8*)(&As[b][(wr * 64 + 48 + lr) * 32 + sq]); \
    bf16x8 t0 = *(const bf16x8*)(&B1s[b][(wc * 64 +  0 + lr) * 32 + sq]); \
    bf16x8 t1 = *(const bf16x8*)(&B1s[b][(wc * 64 + 16 + lr) * 32 + sq]); \
    BAR_LGK0(); \
    __builtin_amdgcn_s_setprio(1); \
    acc1[0][0] = __builtin_amdgcn_mfma_f32_16x16x32_bf16(av0, t0, acc1[0][0], 0, 0, 0); \
    acc1[1][0] = __builtin_amdgcn_mfma_f32_16x16x32_bf16(av1, t0, acc1[1][0], 0, 0, 0); \
    acc1[2][0] = __builtin_amdgcn_mfma_f32_16x16x32_bf16(av2, t0, acc1[2][0], 0, 0, 0); \
    acc1[3][0] = __builtin_amdgcn_mfma_f32_16x16x32_bf16(av3, t0, acc1[3][0], 0, 0, 0); \
    acc1[0][1] = __builtin_amdgcn_mfma_f32_16x16x32_bf16(av0, t1, acc1[0][1], 0, 0, 0); \
    acc1[1][1] = __builtin_amdgcn_mfma_f32_16x16x32_bf16(av1, t1, acc1[1][1], 0, 0, 0); \
    acc1[2][1] = __builtin_amdgcn_mfma_f32_16x16x32_bf16(av2, t1, acc1[2][1], 0, 0, 0); \
    acc1[3][1] = __builtin_amdgcn_mfma_f32_16x16x32_bf16(av3, t1, acc1[3][1], 0, 0, 0); \
    __builtin_amdgcn_s_setprio(0); \
    BARP(); \
    t0 = *(const bf16x8*)(&B3s[b][(wc * 64 +  0 + lr) * 32 + sq]); \
    t1 = *(const bf16x8*)(&B3s[b][(wc * 64 + 16 + lr) * 32 + sq]); \
    BAR_LGK0(); \
    __builtin_amdgcn_s_setprio(1); \
    acc3[0][0] = __builtin_amdgcn_mfma_f32_16x16x32_bf16(av0, t0, acc3[0][0], 0, 0, 0); \
    acc3[1][0] = __builtin_amdgcn_mfma_f32_16x16x32_bf16(av1, t0, acc3[1][0], 0, 0, 0); \
    acc3[2][0] = __builtin_amdgcn_mfma_f32_16x16x32_bf16(av2, t0, acc3[2][0], 0, 0, 0); \
    acc3[3][0] = __builtin_amdgcn_mfma_f32_16x16x32_bf16(av3, t0, acc3[3][0], 0, 0, 0); \
    acc3[0][1] = __builtin_amdgcn_mfma_f32_16x16x32_bf16(av0, t1, acc3[0][1], 0, 0, 0); \
    acc3[1][1] = __builtin_amdgcn_mfma_f32_16x16x32_bf16(av1, t1, acc3[1][1], 0, 0, 0); \
    acc3[2][1] = __builtin_amdgcn_mfma_f32_16x16x32_bf16(av2, t1, acc3[2][1], 0, 0, 0); \
    acc3[3][1] = __builtin_amdgcn_mfma_f32_16x16x32_bf16(av3, t1, acc3[3][1], 0, 0, 0); \
    __builtin_amdgcn_s_setprio(0); \
    BARP(); \
    t0 = *(const bf16x8*)(&B1s[b][(wc * 64 + 32 + lr) * 32 + sq]); \
    t1 = *(const bf16x8*)(&B1s[b][(wc * 64 + 48 + lr) * 32 + sq]); \
    BAR_LGK0(); \
    __builtin_amdgcn_s_setprio(1); \
    acc1[0][2] = __builtin_amdgcn_mfma_f32_16x16x32_bf16(av0, t0, acc1[0][2], 0, 0, 0); \
    acc1[1][2] = __builtin_amdgcn_mfma_f32_16x16x32_bf16(av1, t0, acc1[1][2], 0, 0, 0); \
    acc1[2][2] = __builtin_amdgcn_mfma_f32_16x16x32_bf16(av2, t0, acc1[2][2], 0, 0, 0); \
    acc1[3][2] = __builtin_amdgcn_mfma_f32_16x16x32_bf16(av3, t0, acc1[3][2], 0, 0, 0); \
    acc1[0][3] = __builtin_amdgcn_mfma_f32_16x16x32_bf16(av0, t1, acc1[0][3], 0, 0, 0); \
    acc1[1][3] = __builtin_amdgcn_mfma_f32_16x16x32_bf16(av1, t1, acc1[1][3], 0, 0, 0); \
    acc1[2][3] = __builtin_amdgcn_mfma_f32_16x16x32_bf16(av2, t1, acc1[2][3], 0, 0, 0); \
    acc1[3][3] = __builtin_amdgcn_mfma_f32_16x16x32_bf16(av3, t1, acc1[3][3], 0, 0, 0); \
    __builtin_amdgcn_s_setprio(0); \
    BARP(); \
    t0 = *(const bf16x8*)(&B3s[b][(wc * 64 + 32 + lr) * 32 + sq]); \
    t1 = *(const bf16x8*)(&B3s[b][(wc * 64 + 48 + lr) * 32 + sq]); \
    BAR_LGK0(); \
    __builtin_amdgcn_s_setprio(1); \
    acc3[0][2] = __builtin_amdgcn_mfma_f32_16x16x32_bf16(av0, t0, acc3[0][2], 0, 0, 0); \
    acc3[1][2] = __builtin_amdgcn_mfma_f32_16x16x32_bf16(av1, t0, acc3[1][2], 0, 0, 0); \
    acc3[2][2] = __builtin_amdgcn_mfma_f32_16x16x32_bf16(av2, t0, acc3[2][2], 0, 0, 0); \
    acc3[3][2] = __builtin_amdgcn_mfma_f32_16x16x32_bf16(av3, t0, acc3[3][2], 0, 0, 0); \
    acc3[0][3] = __builtin_amdgcn_mfma_f32_16x16x32_bf16(av0, t1, acc3[0][3], 0, 0, 0); \
    acc3[1][3] = __builtin_amdgcn_mfma_f32_16x16x32_bf16(av1, t1, acc3[1][3], 0, 0, 0); \
    acc3[2][3] = __builtin_amdgcn_mfma_f32_16x16x32_bf16(av2, t1, acc3[2][3], 0, 0, 0); \
    acc3[3][3] = __builtin_amdgcn_mfma_f32_16x16x32_bf16(av3, t1, acc3[3][3], 0, 0, 0); \
    __builtin_amdgcn_s_setprio(0); \
    BARP(); \
  } while (0)

  for (int mt = z; mt * 256 < cnt; mt += 4) {
    const int row0 = mt * 256;
    int s0 = row0 + r0;       if (s0 >= cnt) s0 = cnt - 1;
    int s1 = row0 + 128 + r0; if (s1 >= cnt) s1 = cnt - 1;
    const unsigned short* a0g = xb + (size_t)pair_token[base + s0] * Dm + c0;
    const unsigned short* a1g = xb + (size_t)pair_token[base + s1] * Dm + c0;

    f32x4 acc1[4][4], acc3[4][4];
#pragma unroll
    for (int m = 0; m < 4; ++m)
#pragma unroll
      for (int n = 0; n < 4; ++n) {
        acc1[m][n] = (f32x4){0.f, 0.f, 0.f, 0.f};
        acc3[m][n] = (f32x4){0.f, 0.f, 0.f, 0.f};
      }

    STG(0, 0);
    STG(1, 32);
    int cur = 0;
    for (int t = 0; t < 62; ++t) {          // K-steps 0..61 (NK=64)
      int sb = cur + 2; if (sb >= 3) sb -= 3;
      STG(sb, (t + 2) * 32);                // stage K-step t+2
      WAIT8_BAR();                          // cur's 4 loads landed (12 in flight -> 8)
      PHASES(cur);
      cur = (cur == 2) ? 0 : cur + 1;
    }
    WAIT4_BAR();                            // K-step 62
    PHASES(cur);
    cur = (cur == 2) ? 0 : cur + 1;
    WAIT0_BAR();                            // K-step 63
    PHASES(cur);

#pragma unroll
    for (int m = 0; m < 4; ++m) {
      const int rb = wr * 64 + m * 16 + ((l >> 4) << 2);
#pragma unroll
      for (int i = 0; i < 4; ++i) {
        const int sl2 = row0 + rb + i;
        if (sl2 < cnt) {
          unsigned short* hrow = h + (size_t)(base + sl2) * HP + j0 + wc * 64 + lr;
#pragma unroll
          for (int n = 0; n < 4; ++n) {
            const float aa = acc1[m][n][i];
            const float g = aa / (1.f + __expf(-aa));
            hrow[n * 16] = f2bf(g * acc3[m][n][i]);
          }
        }
      }
    }
  }
#undef STG
#undef PHASES
}

// ---------------- GEMM2: y[slot] = h[slot] w2^T (plain stores) ----------------
// 128x128 tile, BK=64, dbuf + counted vmcnt + 3-bit XOR swizzle. (round-16 proven)
__global__ __launch_bounds__(256, 2) void gemm2_kernel(
    const unsigned short* __restrict__ h, const unsigned short* __restrict__ w2b,
    const int* __restrict__ counts, const int* __restrict__ offs,
    float* __restrict__ y)
{
  const int bid = blockIdx.x;
  const int logical = (bid & 7) * 128 + (bid >> 3);
  const int z  = logical & 7;
  const int pe = logical >> 3;
  const int e  = pe & 7;
  const int dp = pe >> 3;

  const int cnt = counts[e];
  if (cnt <= 0) return;
  const int base = offs[e];
  const int d0 = dp * 128;
  const int tid = threadIdx.x;
  const int l = tid & 63;
  const int wid = tid >> 6;
  const int wr = wid >> 1, wc = wid & 1;

  __shared__ unsigned short Ah[2][128 * 64];
  __shared__ unsigned short Bs[2][128 * 64];

  const int r0 = tid >> 3;
  const int c0 = (((tid & 7) ^ ((tid >> 3) & 7))) * 8;

  const unsigned short* br0 = w2b + ((size_t)e * Dm + d0 + r0)      * HP + c0;
  const unsigned short* br1 = w2b + ((size_t)e * Dm + d0 + r0 + 32) * HP + c0;
  const unsigned short* br2 = w2b + ((size_t)e * Dm + d0 + r0 + 64) * HP + c0;
  const unsigned short* br3 = w2b + ((size_t)e * Dm + d0 + r0 + 96) * HP + c0;

  const int wbA0 = (0 * 256 + wid * 64) * 8;
  const int wbA1 = (1 * 256 + wid * 64) * 8;
  const int wbA2 = (2 * 256 + wid * 64) * 8;
  const int wbA3 = (3 * 256 + wid * 64) * 8;

  const int lr = l & 15;
  const int sq0 = (((0 * 4 + (l >> 4)) ^ (lr & 7))) * 8;
  const int sq1 = (((1 * 4 + (l >> 4)) ^ (lr & 7))) * 8;

#define STAGE2(b, kk) do { \
    gl16(a0 + (kk), &Ah[b][wbA0]); gl16(a1 + (kk), &Ah[b][wbA1]); \
    gl16(a2 + (kk), &Ah[b][wbA2]); gl16(a3 + (kk), &Ah[b][wbA3]); \
    gl16(br0 + (kk), &Bs[b][wbA0]); gl16(br1 + (kk), &Bs[b][wbA1]); \
    gl16(br2 + (kk), &Bs[b][wbA2]); gl16(br3 + (kk), &Bs[b][wbA3]); \
  } while (0)

#define COMPUTE2(b) do { \
    bf16x8 av[4], bv[4]; \
    _Pragma("unroll") \
    for (int m = 0; m < 4; ++m) \
      av[m] = *(const bf16x8*)(&Ah[b][(wr * 64 + m * 16 + lr) * 64 + sq0]); \
    _Pragma("unroll") \
    for (int n = 0; n < 4; ++n) \
      bv[n] = *(const bf16x8*)(&Bs[b][(wc * 64 + n * 16 + lr) * 64 + sq0]); \
    _Pragma("unroll") \
    for (int m = 0; m < 4; ++m) \
      _Pragma("unroll") \
      for (int n = 0; n < 4; ++n) \
        acc[m][n] = __builtin_amdgcn_mfma_f32_16x16x32_bf16(av[m], bv[n], acc[m][n], 0, 0, 0); \
    _Pragma("unroll") \
    for (int m = 0; m < 4; ++m) \
      av[m] = *(const bf16x8*)(&Ah[b][(wr * 64 + m * 16 + lr) * 64 + sq1]); \
    _Pragma("unroll") \
    for (int n = 0; n < 4; ++n) \
      bv[n] = *(const bf16x8*)(&Bs[b][(wc * 64 + n * 16 + lr) * 64 + sq1]); \
    _Pragma("unroll") \
    for (int m = 0; m < 4; ++m) \
      _Pragma("unroll") \
      for (int n = 0; n < 4; ++n) \
        acc[m][n] = __builtin_amdgcn_mfma_f32_16x16x32_bf16(av[m], bv[n], acc[m][n], 0, 0, 0); \
  } while (0)

  for (int mt = z; mt * 128 < cnt; mt += 8) {
    const int row0 = mt * 128;
    int s0 = row0 + r0;      if (s0 >= cnt) s0 = cnt - 1;
    int s1 = row0 + r0 + 32; if (s1 >= cnt) s1 = cnt - 1;
    int s2 = row0 + r0 + 64; if (s2 >= cnt) s2 = cnt - 1;
    int s3 = row0 + r0 + 96; if (s3 >= cnt) s3 = cnt - 1;
    const unsigned short* a0 = h + (size_t)(base + s0) * HP + c0;
    const unsigned short* a1 = h + (size_t)(base + s1) * HP + c0;
    const unsigned short* a2 = h + (size_t)(base + s2) * HP + c0;
    const unsigned short* a3 = h + (size_t)(base + s3) * HP + c0;

    f32x4 acc[4][4];
#pragma unroll
    for (int m = 0; m < 4; ++m)
#pragma unroll
      for (int n = 0; n < 4; ++n) acc[m][n] = (f32x4){0.f, 0.f, 0.f, 0.f};

    STAGE2(0, 0);
    int cur = 0;
    for (int kk = 0; kk < HP - 64; kk += 64) {
      STAGE2(cur ^ 1, kk + 64);
      WAIT8_BAR();
      COMPUTE2(cur);
      LGK0_BAR();
      cur ^= 1;
    }
    WAIT0_BAR();
    COMPUTE2(cur);
    LGK0_BAR();

#pragma unroll
    for (int m = 0; m < 4; ++m) {
      const int rb = row0 + wr * 64 + m * 16 + ((l >> 4) << 2);
#pragma unroll
      for (int i = 0; i < 4; ++i) {
        const int sl2 = rb + i;
        if (sl2 < cnt) {
          float* yrow = y + (size_t)(base + sl2) * Dm + d0 + wc * 64 + lr;
#pragma unroll
          for (int n = 0; n < 4; ++n)
            yrow[n * 16] = acc[m][n][i];
        }
      }
    }
  }
#undef STAGE2
#undef COMPUTE2
}

// ---------------- combine: out[t] = w0*y[slot0] + w1*y[slot1] ----------------
__global__ __launch_bounds__(256) void combine_kernel(
    const float* __restrict__ y, const int* __restrict__ slot_of,
    const float* __restrict__ topk_p, float* __restrict__ out)
{
  const int t = blockIdx.x;
  const int s0 = slot_of[t * 2], s1 = slot_of[t * 2 + 1];
  const float w0 = topk_p[t * 2], w1 = topk_p[t * 2 + 1];
  const float* y0 = y + (size_t)s0 * Dm;
  const float* y1 = y + (size_t)s1 * Dm;
  float* o = out + (size_t)t * Dm;
  const int c = threadIdx.x * 8;
  float4 a0 = *(const float4*)(y0 + c);
  float4 a1 = *(const float4*)(y0 + c + 4);
  float4 b0 = *(const float4*)(y1 + c);
  float4 b1 = *(const float4*)(y1 + c + 4);
  float4 r0, r1;
  r0.x = w0 * a0.x + w1 * b0.x; r0.y = w0 * a0.y + w1 * b0.y;
  r0.z = w0 * a0.z + w1 * b0.z; r0.w = w0 * a0.w + w1 * b0.w;
  r1.x = w0 * a1.x + w1 * b1.x; r1.y = w0 * a1.y + w1 * b1.y;
  r1.z = w0 * a1.z + w1 * b1.z; r1.w = w0 * a1.w + w1 * b1.w;
  *(float4*)(o + c) = r0;
  *(float4*)(o + c + 4) = r1;
}

extern "C" void kernel_launch(void* const* d_in, const int* in_sizes, int n_in,
                              void* d_out, int out_size, void* d_ws, size_t ws_size,
                              hipStream_t stream) {
  const float* x  = (const float*)d_in[0];
  const float* wg = (const float*)d_in[1];
  const float* w1 = (const float*)d_in[2];
  const float* w2 = (const float*)d_in[3];
  const float* w3 = (const float*)d_in[4];
  float* out = (float*)d_out;

  char* ws = (char*)d_ws;
  int*    counts     = (int*)(ws + 64);
  int*    offs       = (int*)(ws + 128);
  int*    topk_e     = (int*)(ws + 1024);
  float*  topk_p     = (float*)(ws + 40960);
  int*    pair_token = (int*)(ws + 81920);
  float*  gate_p     = (float*)(ws + 163840);
  int*    slot_of    = (int*)(ws + 307200);
  const size_t MB = 1u << 20;
  unsigned short* xb  = (unsigned short*)(ws + 1 * MB);    // 16 MiB
  unsigned short* h   = (unsigned short*)(ws + 17 * MB);   // 86 MiB
  unsigned short* w1b = (unsigned short*)(ws + 104 * MB);  // 172 MiB
  unsigned short* w3b = (unsigned short*)(ws + 276 * MB);  // 172 MiB
  unsigned short* w2b = (unsigned short*)(ws + 448 * MB);  // 172 MiB -> ends 620 MiB
  // y reuses w1b's region (stream-ordered: gemm1 done with w1b before gemm2).
  float* y = (float*)(ws + 104 * MB);                      // 64 MiB

  gating_kernel  <<<Tn, 64, 0, stream>>>(x, wg, gate_p, topk_e, topk_p, xb);
  reduce_scatter_kernel<<<1, 256, 0, stream>>>(topk_e, topk_p, gate_p, counts, offs,
                                               pair_token, slot_of, out + (size_t)Tn * Dm);
  cvt_w13_kernel <<<dim3(En * HP * Dm / 8 / 256, 2), 256, 0, stream>>>(w1, w3, w1b, w3b);
  cvt_w2_kernel  <<<En * Dm * HP / 8 / 256, 256, 0, stream>>>(w2, w2b);
  gemm1_kernel   <<<43 * En * 4, 512, 0, stream>>>(xb, w1b, w3b, counts, offs, pair_token, h);
  gemm2_kernel   <<<(Dm / 128) * En * 8, 256, 0, stream>>>(h, w2b, counts, offs, y);
  combine_kernel <<<Tn, 256, 0, stream>>>(y, slot_of, topk_p, out);
}

// Round 18
// 1569.076 us; speedup vs baseline: 1.0802x; 1.0802x over previous
//
#include <hip/hip_runtime.h>
#include <hip/hip_bf16.h>

#define Tn 4096
#define Dm 2048
#define En 8
#define Hh 5461
#define HP 5504   // 43 * 128 = 86 * 64

typedef __attribute__((ext_vector_type(8))) short bf16x8;
typedef __attribute__((ext_vector_type(4))) float f32x4;

__device__ __forceinline__ unsigned short f2bf(float f) {
  union { __hip_bfloat16 b; unsigned short u; } c;
  c.b = __float2bfloat16(f);
  return c.u;
}

__device__ __forceinline__ uint4 pack8(const float* f) {
  union { unsigned short us[8]; uint4 v; } o;
#pragma unroll
  for (int i = 0; i < 8; ++i) o.us[i] = f2bf(f[i]);
  return o.v;
}

__device__ __forceinline__ bf16x8 cvt8(float4 a, float4 b) {
  union { unsigned short us[8]; bf16x8 v; } o;
  o.us[0] = f2bf(a.x); o.us[1] = f2bf(a.y); o.us[2] = f2bf(a.z); o.us[3] = f2bf(a.w);
  o.us[4] = f2bf(b.x); o.us[5] = f2bf(b.y); o.us[6] = f2bf(b.z); o.us[7] = f2bf(b.w);
  return o.v;
}

// async 16B global -> LDS. lds must be wave-uniform; HW adds lane*16.
__device__ __forceinline__ void gl16(const void* g, void* lds) {
  __builtin_amdgcn_global_load_lds(
      (const __attribute__((address_space(1))) unsigned int*)g,
      (__attribute__((address_space(3))) unsigned int*)lds, 16, 0, 0);
}

// FUSED counted-wait + barrier. Single asm block.
#define WAIT10_BAR() asm volatile("s_waitcnt vmcnt(10)\n\ts_barrier" ::: "memory")
#define WAIT8_BAR()  asm volatile("s_waitcnt vmcnt(8)\n\ts_barrier" ::: "memory")
#define WAIT0_BAR()  asm volatile("s_waitcnt vmcnt(0)\n\ts_barrier" ::: "memory")
// Trailing barrier: drain own LDS reads (lgkmcnt only) then barrier.
#define LGK0_BAR()   asm volatile("s_waitcnt lgkmcnt(0)\n\ts_barrier" ::: "memory")

// LDS 16B-unit XOR swizzles (bank-conflict-free, verified r8/9 pattern).

// ---------------- gating: logits + probs + top-2 + fused x->bf16 ----------------
__global__ __launch_bounds__(64) void gating_kernel(
    const float* __restrict__ x, const float* __restrict__ wg,
    float* __restrict__ gate_p, int* __restrict__ topk_e, float* __restrict__ topk_p,
    unsigned short* __restrict__ xb)
{
  const int t = blockIdx.x;
  const int l = threadIdx.x;
  const float* xr = x + (size_t)t * Dm;
  float acc[En];
#pragma unroll
  for (int e = 0; e < En; ++e) acc[e] = 0.f;
  for (int d = l; d < Dm; d += 64) {
    const float xv = xr[d];
#pragma unroll
    for (int e = 0; e < En; ++e) acc[e] = fmaf(xv, wg[e * Dm + d], acc[e]);
  }
#pragma unroll
  for (int e = 0; e < En; ++e) {
    float v = acc[e];
#pragma unroll
    for (int s = 32; s > 0; s >>= 1) v += __shfl_xor(v, s);
    acc[e] = v;
  }
  unsigned short* xrow = xb + (size_t)t * Dm;
#pragma unroll
  for (int k = 0; k < 4; ++k) {
    const int b = k * 512 + l * 8;
    float f[8];
    *(float4*)(f)     = *(const float4*)(xr + b);
    *(float4*)(f + 4) = *(const float4*)(xr + b + 4);
    *(uint4*)(xrow + b) = pack8(f);
  }
  if (l == 0) {
    float m = acc[0];
    for (int e = 1; e < En; ++e) m = fmaxf(m, acc[e]);
    float p[En]; float s = 0.f;
    for (int e = 0; e < En; ++e) { p[e] = __expf(acc[e] - m); s += p[e]; }
    const float inv = 1.f / s;
    for (int e = 0; e < En; ++e) gate_p[t * En + e] = p[e] * inv;
    int e0 = 0; float v0 = acc[0];
    for (int e = 1; e < En; ++e) if (acc[e] > v0) { v0 = acc[e]; e0 = e; }
    int e1 = -1; float v1 = -3.4e38f;
    for (int e = 0; e < En; ++e) if (e != e0 && acc[e] > v1) { v1 = acc[e]; e1 = e; }
    const float q  = __expf(v1 - v0);
    const float q0 = 1.f / (1.f + q);
    const float q1 = q * q0;
    topk_e[t * 2] = e0; topk_e[t * 2 + 1] = e1;
    topk_p[t * 2] = q0; topk_p[t * 2 + 1] = q1;
  }
}

// ---------------- reduce+scatter (single block, LDS atomics only) ----------------
__global__ __launch_bounds__(256) void reduce_scatter_kernel(
    const int* __restrict__ topk_e, const float* __restrict__ topk_p,
    const float* __restrict__ gate_p,
    int* __restrict__ counts, int* __restrict__ offs,
    int* __restrict__ pair_token, int* __restrict__ slot_of,
    float* __restrict__ out_scalar)
{
  __shared__ int cnt_s[En];
  __shared__ int run_s[En];
  __shared__ float red[256 * En];
  const int tid = threadIdx.x;
  if (tid < En) cnt_s[tid] = 0;
  __syncthreads();
  for (int i = tid; i < Tn * 2; i += 256) atomicAdd(&cnt_s[topk_e[i]], 1);
  __syncthreads();
  if (tid == 0) {
    int o = 0;
    for (int e = 0; e < En; ++e) {
      offs[e] = o; run_s[e] = o; counts[e] = cnt_s[e]; o += cnt_s[e];
    }
  }
  __syncthreads();
  for (int i = tid; i < Tn * 2; i += 256) {
    const int e = topk_e[i];
    const int slot = atomicAdd(&run_s[e], 1);
    pair_token[slot] = i >> 1;
    slot_of[i] = slot;
  }
  float p8[En];
#pragma unroll
  for (int e = 0; e < En; ++e) p8[e] = 0.f;
  for (int t = tid; t < Tn; t += 256)
#pragma unroll
    for (int e = 0; e < En; ++e) p8[e] += gate_p[t * En + e];
#pragma unroll
  for (int e = 0; e < En; ++e) red[tid * En + e] = p8[e];
  __syncthreads();
  for (int s = 128; s > 0; s >>= 1) {
    if (tid < s)
#pragma unroll
      for (int e = 0; e < En; ++e) red[tid * En + e] += red[(tid + s) * En + e];
    __syncthreads();
  }
  if (tid == 0) {
    double mp[En]; double sum = 0.0;
    for (int e = 0; e < En; ++e) { mp[e] = (double)red[e] / (double)Tn; sum += mp[e]; }
    const double mean = sum / En;
    double var = 0.0;
    for (int e = 0; e < En; ++e) { const double d = mp[e] - mean; var += d * d; }
    var /= (En - 1);
    const double denom = mean + 1e-10;
    *out_scalar = (float)(0.01 * var / (denom * denom));
  }
}

// ---------------- w2 fp32 [E][Dm][Hh] -> bf16 [E][Dm][HP], pad cols zero ----------------
__global__ __launch_bounds__(256) void cvt_w2_kernel(const float* __restrict__ w2,
                                                     unsigned short* __restrict__ w2b)
{
  const unsigned i = ((unsigned)blockIdx.x * 256u + threadIdx.x) * 8u;
  const unsigned per_e = (unsigned)Dm * HP;
  const unsigned e = i / per_e;
  const unsigned r = i % per_e;
  const unsigned row = r / HP, col = r % HP;
  const float* s = w2 + (size_t)e * Dm * Hh + (size_t)row * Hh + col;
  float f[8];
#pragma unroll
  for (int k = 0; k < 8; ++k) f[k] = (col + k < Hh) ? s[k] : 0.f;
  *(uint4*)(w2b + i) = pack8(f);
}

// ---------------- GEMM1: h = silu(x w1^T) * (x w3^T), routed ----------------
// 128x128 tile, BK=32, round-16 2-phase sync; B staged DIRECTLY from fp32 w1/w3
// into fp32 LDS (gl16), converted to bf16 after ds_read. No cvt_w13 pass.
__global__ __launch_bounds__(256, 2) void gemm1_kernel(
    const unsigned short* __restrict__ xb,
    const float* __restrict__ w1, const float* __restrict__ w3,
    const int* __restrict__ counts, const int* __restrict__ offs,
    const int* __restrict__ pair_token,
    unsigned short* __restrict__ h)
{
  // nwg = 43*8*8 = 2752; chunk = 344 (bijective XCD remap)
  const int bid = blockIdx.x;
  const int logical = (bid & 7) * 344 + (bid >> 3);
  const int z  = logical & 7;
  const int pe = logical >> 3;
  const int e  = pe & 7;
  const int jp = pe >> 3;

  const int cnt = counts[e];
  if (cnt <= 0) return;
  const int base = offs[e];
  const int j0 = jp * 128;
  const int tid = threadIdx.x;
  const int l = tid & 63;
  const int wid = tid >> 6;
  const int wr = wid >> 1, wc = wid & 1;

  __shared__ unsigned short As[2][128 * 32];   // bf16 A: 8 KB/buf
  __shared__ float B1f[2][128 * 32];           // fp32 B1: 16 KB/buf
  __shared__ float B3f[2][128 * 32];           // fp32 B3: 16 KB/buf -> 80 KB total

  // ---- A staging (bf16, 2 lines): unit u = i*256+tid, row=u>>2, 2-bit swizzle
  const int rA0 = tid >> 2;
  const int cA0 = (((tid & 3) ^ ((tid >> 3) & 3))) * 8;  // bf16 elems
  const int wbA0 = wid * 512;             // elem base (unit=8 bf16)
  const int wbA1 = 2048 + wid * 512;

  // ---- B staging (fp32, 4 lines each): unit u = i*256+tid, row=u>>3 (=32i+(tid>>3)),
  // 3-bit swizzle: physical p=u&7 holds source col-unit q = p ^ (row&7).
  const int rBl = tid >> 3;                               // 0..31 local
  const int cBf = (((tid & 7) ^ ((tid >> 3) & 7))) * 4;   // fp32 elems
  // clamped global rows (pad rows read garbage; epilogue zeroes cols >= Hh)
  int rB0 = j0 + rBl;      if (rB0 >= Hh) rB0 = Hh - 1;
  int rB1 = j0 + 32 + rBl; if (rB1 >= Hh) rB1 = Hh - 1;
  int rB2 = j0 + 64 + rBl; if (rB2 >= Hh) rB2 = Hh - 1;
  int rB3 = j0 + 96 + rBl; if (rB3 >= Hh) rB3 = Hh - 1;
  const float* b1g0 = w1 + ((size_t)e * Hh + rB0) * Dm + cBf;
  const float* b1g1 = w1 + ((size_t)e * Hh + rB1) * Dm + cBf;
  const float* b1g2 = w1 + ((size_t)e * Hh + rB2) * Dm + cBf;
  const float* b1g3 = w1 + ((size_t)e * Hh + rB3) * Dm + cBf;
  const float* b3g0 = w3 + ((size_t)e * Hh + rB0) * Dm + cBf;
  const float* b3g1 = w3 + ((size_t)e * Hh + rB1) * Dm + cBf;
  const float* b3g2 = w3 + ((size_t)e * Hh + rB2) * Dm + cBf;
  const float* b3g3 = w3 + ((size_t)e * Hh + rB3) * Dm + cBf;
  const int wbF0 = (0 * 256 + wid * 64) * 4;   // fp32 elem bases (unit=4 f32)
  const int wbF1 = (1 * 256 + wid * 64) * 4;
  const int wbF2 = (2 * 256 + wid * 64) * 4;
  const int wbF3 = (3 * 256 + wid * 64) * 4;

  const int lr = l & 15;
  const int sqA = (((l >> 4) ^ ((lr >> 1) & 3))) * 8;      // A read (bf16 elems)
  const int qB  = 2 * (l >> 4);
  const int pB0 = ((qB)     ^ (lr & 7)) * 4;               // B read (fp32 elems)
  const int pB1 = ((qB + 1) ^ (lr & 7)) * 4;

#define STAGE1(b, kk) do { \
    gl16(a0g + (kk), &As[b][wbA0]);  gl16(a1g + (kk), &As[b][wbA1]); \
    gl16(b1g0 + (kk), &B1f[b][wbF0]); gl16(b1g1 + (kk), &B1f[b][wbF1]); \
    gl16(b1g2 + (kk), &B1f[b][wbF2]); gl16(b1g3 + (kk), &B1f[b][wbF3]); \
    gl16(b3g0 + (kk), &B3f[b][wbF0]); gl16(b3g1 + (kk), &B3f[b][wbF1]); \
    gl16(b3g2 + (kk), &B3f[b][wbF2]); gl16(b3g3 + (kk), &B3f[b][wbF3]); \
  } while (0)

#define COMPUTE1(b) do { \
    bf16x8 av[4], b1v[4], b3v[4]; \
    _Pragma("unroll") \
    for (int m = 0; m < 4; ++m) \
      av[m] = *(const bf16x8*)(&As[b][(wr * 64 + m * 16 + lr) * 32 + sqA]); \
    _Pragma("unroll") \
    for (int n = 0; n < 4; ++n) { \
      const int rw = (wc * 64 + n * 16 + lr) * 32; \
      float4 f0 = *(const float4*)(&B1f[b][rw + pB0]); \
      float4 f1 = *(const float4*)(&B1f[b][rw + pB1]); \
      b1v[n] = cvt8(f0, f1); \
      f0 = *(const float4*)(&B3f[b][rw + pB0]); \
      f1 = *(const float4*)(&B3f[b][rw + pB1]); \
      b3v[n] = cvt8(f0, f1); \
    } \
    _Pragma("unroll") \
    for (int m = 0; m < 4; ++m) \
      _Pragma("unroll") \
      for (int n = 0; n < 4; ++n) { \
        acc1[m][n] = __builtin_amdgcn_mfma_f32_16x16x32_bf16(av[m], b1v[n], acc1[m][n], 0, 0, 0); \
        acc3[m][n] = __builtin_amdgcn_mfma_f32_16x16x32_bf16(av[m], b3v[n], acc3[m][n], 0, 0, 0); \
      } \
  } while (0)

  for (int mt = z; mt * 128 < cnt; mt += 8) {
    const int row0 = mt * 128;
    int s0 = row0 + rA0;      if (s0 >= cnt) s0 = cnt - 1;
    int s1 = row0 + 64 + rA0; if (s1 >= cnt) s1 = cnt - 1;
    const unsigned short* a0g = xb + (size_t)pair_token[base + s0] * Dm + cA0;
    const unsigned short* a1g = xb + (size_t)pair_token[base + s1] * Dm + cA0;

    f32x4 acc1[4][4], acc3[4][4];
#pragma unroll
    for (int m = 0; m < 4; ++m)
#pragma unroll
      for (int n = 0; n < 4; ++n) {
        acc1[m][n] = (f32x4){0.f, 0.f, 0.f, 0.f};
        acc3[m][n] = (f32x4){0.f, 0.f, 0.f, 0.f};
      }

    STAGE1(0, 0);
    int cur = 0;
    for (int kk = 0; kk < Dm - 32; kk += 32) {
      STAGE1(cur ^ 1, kk + 32);   // prefetch next K-step (10 more in flight)
      WAIT10_BAR();               // current buffer's 10 loads landed (all waves)
      COMPUTE1(cur);
      LGK0_BAR();                 // drain own ds_reads (NOT vmcnt) + barrier
      cur ^= 1;
    }
    WAIT0_BAR();
    COMPUTE1(cur);
    LGK0_BAR();

    const int colb = j0 + wc * 64 + lr;
#pragma unroll
    for (int m = 0; m < 4; ++m) {
      const int rb = wr * 64 + m * 16 + ((l >> 4) << 2);
#pragma unroll
      for (int i = 0; i < 4; ++i) {
        const int sl2 = row0 + rb + i;
        if (sl2 < cnt) {
          unsigned short* hrow = h + (size_t)(base + sl2) * HP + colb;
#pragma unroll
          for (int n = 0; n < 4; ++n) {
            const float aa = acc1[m][n][i];
            const float g = aa / (1.f + __expf(-aa));
            // pad cols (>= Hh) must be ZERO (gemm2 uses them as K elements)
            const float hv = (colb + n * 16 < Hh) ? g * acc3[m][n][i] : 0.f;
            hrow[n * 16] = f2bf(hv);
          }
        }
      }
    }
  }
#undef STAGE1
#undef COMPUTE1
}

// ---------------- GEMM2: y[slot] = h[slot] w2^T (plain stores) ----------------
// 128x128 tile, BK=64, dbuf + counted vmcnt + 3-bit XOR swizzle. (round-16 proven)
__global__ __launch_bounds__(256, 2) void gemm2_kernel(
    const unsigned short* __restrict__ h, const unsigned short* __restrict__ w2b,
    const int* __restrict__ counts, const int* __restrict__ offs,
    float* __restrict__ y)
{
  const int bid = blockIdx.x;
  const int logical = (bid & 7) * 128 + (bid >> 3);
  const int z  = logical & 7;
  const int pe = logical >> 3;
  const int e  = pe & 7;
  const int dp = pe >> 3;

  const int cnt = counts[e];
  if (cnt <= 0) return;
  const int base = offs[e];
  const int d0 = dp * 128;
  const int tid = threadIdx.x;
  const int l = tid & 63;
  const int wid = tid >> 6;
  const int wr = wid >> 1, wc = wid & 1;

  __shared__ unsigned short Ah[2][128 * 64];
  __shared__ unsigned short Bs[2][128 * 64];

  const int r0 = tid >> 3;
  const int c0 = (((tid & 7) ^ ((tid >> 3) & 7))) * 8;

  const unsigned short* br0 = w2b + ((size_t)e * Dm + d0 + r0)      * HP + c0;
  const unsigned short* br1 = w2b + ((size_t)e * Dm + d0 + r0 + 32) * HP + c0;
  const unsigned short* br2 = w2b + ((size_t)e * Dm + d0 + r0 + 64) * HP + c0;
  const unsigned short* br3 = w2b + ((size_t)e * Dm + d0 + r0 + 96) * HP + c0;

  const int wbA0 = (0 * 256 + wid * 64) * 8;
  const int wbA1 = (1 * 256 + wid * 64) * 8;
  const int wbA2 = (2 * 256 + wid * 64) * 8;
  const int wbA3 = (3 * 256 + wid * 64) * 8;

  const int lr = l & 15;
  const int sq0 = (((0 * 4 + (l >> 4)) ^ (lr & 7))) * 8;
  const int sq1 = (((1 * 4 + (l >> 4)) ^ (lr & 7))) * 8;

#define STAGE2(b, kk) do { \
    gl16(a0 + (kk), &Ah[b][wbA0]); gl16(a1 + (kk), &Ah[b][wbA1]); \
    gl16(a2 + (kk), &Ah[b][wbA2]); gl16(a3 + (kk), &Ah[b][wbA3]); \
    gl16(br0 + (kk), &Bs[b][wbA0]); gl16(br1 + (kk), &Bs[b][wbA1]); \
    gl16(br2 + (kk), &Bs[b][wbA2]); gl16(br3 + (kk), &Bs[b][wbA3]); \
  } while (0)

#define COMPUTE2(b) do { \
    bf16x8 av[4], bv[4]; \
    _Pragma("unroll") \
    for (int m = 0; m < 4; ++m) \
      av[m] = *(const bf16x8*)(&Ah[b][(wr * 64 + m * 16 + lr) * 64 + sq0]); \
    _Pragma("unroll") \
    for (int n = 0; n < 4; ++n) \
      bv[n] = *(const bf16x8*)(&Bs[b][(wc * 64 + n * 16 + lr) * 64 + sq0]); \
    _Pragma("unroll") \
    for (int m = 0; m < 4; ++m) \
      _Pragma("unroll") \
      for (int n = 0; n < 4; ++n) \
        acc[m][n] = __builtin_amdgcn_mfma_f32_16x16x32_bf16(av[m], bv[n], acc[m][n], 0, 0, 0); \
    _Pragma("unroll") \
    for (int m = 0; m < 4; ++m) \
      av[m] = *(const bf16x8*)(&Ah[b][(wr * 64 + m * 16 + lr) * 64 + sq1]); \
    _Pragma("unroll") \
    for (int n = 0; n < 4; ++n) \
      bv[n] = *(const bf16x8*)(&Bs[b][(wc * 64 + n * 16 + lr) * 64 + sq1]); \
    _Pragma("unroll") \
    for (int m = 0; m < 4; ++m) \
      _Pragma("unroll") \
      for (int n = 0; n < 4; ++n) \
        acc[m][n] = __builtin_amdgcn_mfma_f32_16x16x32_bf16(av[m], bv[n], acc[m][n], 0, 0, 0); \
  } while (0)

  for (int mt = z; mt * 128 < cnt; mt += 8) {
    const int row0 = mt * 128;
    int s0 = row0 + r0;      if (s0 >= cnt) s0 = cnt - 1;
    int s1 = row0 + r0 + 32; if (s1 >= cnt) s1 = cnt - 1;
    int s2 = row0 + r0 + 64; if (s2 >= cnt) s2 = cnt - 1;
    int s3 = row0 + r0 + 96; if (s3 >= cnt) s3 = cnt - 1;
    const unsigned short* a0 = h + (size_t)(base + s0) * HP + c0;
    const unsigned short* a1 = h + (size_t)(base + s1) * HP + c0;
    const unsigned short* a2 = h + (size_t)(base + s2) * HP + c0;
    const unsigned short* a3 = h + (size_t)(base + s3) * HP + c0;

    f32x4 acc[4][4];
#pragma unroll
    for (int m = 0; m < 4; ++m)
#pragma unroll
      for (int n = 0; n < 4; ++n) acc[m][n] = (f32x4){0.f, 0.f, 0.f, 0.f};

    STAGE2(0, 0);
    int cur = 0;
    for (int kk = 0; kk < HP - 64; kk += 64) {
      STAGE2(cur ^ 1, kk + 64);
      WAIT8_BAR();
      COMPUTE2(cur);
      LGK0_BAR();
      cur ^= 1;
    }
    WAIT0_BAR();
    COMPUTE2(cur);
    LGK0_BAR();

#pragma unroll
    for (int m = 0; m < 4; ++m) {
      const int rb = row0 + wr * 64 + m * 16 + ((l >> 4) << 2);
#pragma unroll
      for (int i = 0; i < 4; ++i) {
        const int sl2 = rb + i;
        if (sl2 < cnt) {
          float* yrow = y + (size_t)(base + sl2) * Dm + d0 + wc * 64 + lr;
#pragma unroll
          for (int n = 0; n < 4; ++n)
            yrow[n * 16] = acc[m][n][i];
        }
      }
    }
  }
#undef STAGE2
#undef COMPUTE2
}

// ---------------- combine: out[t] = w0*y[slot0] + w1*y[slot1] ----------------
__global__ __launch_bounds__(256) void combine_kernel(
    const float* __restrict__ y, const int* __restrict__ slot_of,
    const float* __restrict__ topk_p, float* __restrict__ out)
{
  const int t = blockIdx.x;
  const int s0 = slot_of[t * 2], s1 = slot_of[t * 2 + 1];
  const float w0 = topk_p[t * 2], w1 = topk_p[t * 2 + 1];
  const float* y0 = y + (size_t)s0 * Dm;
  const float* y1 = y + (size_t)s1 * Dm;
  float* o = out + (size_t)t * Dm;
  const int c = threadIdx.x * 8;
  float4 a0 = *(const float4*)(y0 + c);
  float4 a1 = *(const float4*)(y0 + c + 4);
  float4 b0 = *(const float4*)(y1 + c);
  float4 b1 = *(const float4*)(y1 + c + 4);
  float4 r0, r1;
  r0.x = w0 * a0.x + w1 * b0.x; r0.y = w0 * a0.y + w1 * b0.y;
  r0.z = w0 * a0.z + w1 * b0.z; r0.w = w0 * a0.w + w1 * b0.w;
  r1.x = w0 * a1.x + w1 * b1.x; r1.y = w0 * a1.y + w1 * b1.y;
  r1.z = w0 * a1.z + w1 * b1.z; r1.w = w0 * a1.w + w1 * b1.w;
  *(float4*)(o + c) = r0;
  *(float4*)(o + c + 4) = r1;
}

extern "C" void kernel_launch(void* const* d_in, const int* in_sizes, int n_in,
                              void* d_out, int out_size, void* d_ws, size_t ws_size,
                              hipStream_t stream) {
  const float* x  = (const float*)d_in[0];
  const float* wg = (const float*)d_in[1];
  const float* w1 = (const float*)d_in[2];
  const float* w2 = (const float*)d_in[3];
  const float* w3 = (const float*)d_in[4];
  float* out = (float*)d_out;

  char* ws = (char*)d_ws;
  int*    counts     = (int*)(ws + 64);
  int*    offs       = (int*)(ws + 128);
  int*    topk_e     = (int*)(ws + 1024);
  float*  topk_p     = (float*)(ws + 40960);
  int*    pair_token = (int*)(ws + 81920);
  float*  gate_p     = (float*)(ws + 163840);
  int*    slot_of    = (int*)(ws + 307200);
  const size_t MB = 1u << 20;
  unsigned short* xb  = (unsigned short*)(ws + 1 * MB);    // 16 MiB
  unsigned short* h   = (unsigned short*)(ws + 17 * MB);   // 86 MiB
  unsigned short* w2b = (unsigned short*)(ws + 448 * MB);  // 172 MiB -> ends 620 MiB
  float* y = (float*)(ws + 104 * MB);                      // 64 MiB

  gating_kernel  <<<Tn, 64, 0, stream>>>(x, wg, gate_p, topk_e, topk_p, xb);
  reduce_scatter_kernel<<<1, 256, 0, stream>>>(topk_e, topk_p, gate_p, counts, offs,
                                               pair_token, slot_of, out + (size_t)Tn * Dm);
  cvt_w2_kernel  <<<En * Dm * HP / 8 / 256, 256, 0, stream>>>(w2, w2b);
  gemm1_kernel   <<<43 * En * 8, 256, 0, stream>>>(xb, w1, w3, counts, offs, pair_token, h);
  gemm2_kernel   <<<(Dm / 128) * En * 8, 256, 0, stream>>>(h, w2b, counts, offs, y);
  combine_kernel <<<Tn, 256, 0, stream>>>(y, slot_of, topk_p, out);
}

// Round 19
// 1460.971 us; speedup vs baseline: 1.1601x; 1.0740x over previous
//
#include <hip/hip_runtime.h>
#include <hip/hip_bf16.h>

#define Tn 4096
#define Dm 2048
#define En 8
#define Hh 5461
#define HP 5504   // 43 * 128 = 86 * 64

typedef __attribute__((ext_vector_type(8))) short bf16x8;
typedef __attribute__((ext_vector_type(4))) float f32x4;

__device__ __forceinline__ unsigned short f2bf(float f) {
  union { __hip_bfloat16 b; unsigned short u; } c;
  c.b = __float2bfloat16(f);
  return c.u;
}

__device__ __forceinline__ uint4 pack8(const float* f) {
  union { unsigned short us[8]; uint4 v; } o;
#pragma unroll
  for (int i = 0; i < 8; ++i) o.us[i] = f2bf(f[i]);
  return o.v;
}

// async 16B global -> LDS. lds must be wave-uniform; HW adds lane*16.
__device__ __forceinline__ void gl16(const void* g, void* lds) {
  __builtin_amdgcn_global_load_lds(
      (const __attribute__((address_space(1))) unsigned int*)g,
      (__attribute__((address_space(3))) unsigned int*)lds, 16, 0, 0);
}

// FUSED counted-wait + barrier (pre-compute). Single asm block.
#define WAIT8_BAR() asm volatile("s_waitcnt vmcnt(8)\n\ts_barrier" ::: "memory")
#define WAIT6_BAR() asm volatile("s_waitcnt vmcnt(6)\n\ts_barrier" ::: "memory")
#define WAIT0_BAR() asm volatile("s_waitcnt vmcnt(0)\n\ts_barrier" ::: "memory")
// Trailing barrier (post-compute): drain own LDS reads (lgkmcnt only).
#define LGK0_BAR()  asm volatile("s_waitcnt lgkmcnt(0)\n\ts_barrier" ::: "memory")

// LDS 16B-unit XOR swizzle (verified rounds 8/9: SQ_LDS_BANK_CONFLICT -> 0).

// ---------------- gating: logits + probs + top-2 + fused x->bf16 ----------------
__global__ __launch_bounds__(64) void gating_kernel(
    const float* __restrict__ x, const float* __restrict__ wg,
    float* __restrict__ gate_p, int* __restrict__ topk_e, float* __restrict__ topk_p,
    unsigned short* __restrict__ xb)
{
  const int t = blockIdx.x;
  const int l = threadIdx.x;
  const float* xr = x + (size_t)t * Dm;
  float acc[En];
#pragma unroll
  for (int e = 0; e < En; ++e) acc[e] = 0.f;
  for (int d = l; d < Dm; d += 64) {
    const float xv = xr[d];
#pragma unroll
    for (int e = 0; e < En; ++e) acc[e] = fmaf(xv, wg[e * Dm + d], acc[e]);
  }
#pragma unroll
  for (int e = 0; e < En; ++e) {
    float v = acc[e];
#pragma unroll
    for (int s = 32; s > 0; s >>= 1) v += __shfl_xor(v, s);
    acc[e] = v;
  }
  unsigned short* xrow = xb + (size_t)t * Dm;
#pragma unroll
  for (int k = 0; k < 4; ++k) {
    const int b = k * 512 + l * 8;
    float f[8];
    *(float4*)(f)     = *(const float4*)(xr + b);
    *(float4*)(f + 4) = *(const float4*)(xr + b + 4);
    *(uint4*)(xrow + b) = pack8(f);
  }
  if (l == 0) {
    float m = acc[0];
    for (int e = 1; e < En; ++e) m = fmaxf(m, acc[e]);
    float p[En]; float s = 0.f;
    for (int e = 0; e < En; ++e) { p[e] = __expf(acc[e] - m); s += p[e]; }
    const float inv = 1.f / s;
    for (int e = 0; e < En; ++e) gate_p[t * En + e] = p[e] * inv;
    int e0 = 0; float v0 = acc[0];
    for (int e = 1; e < En; ++e) if (acc[e] > v0) { v0 = acc[e]; e0 = e; }
    int e1 = -1; float v1 = -3.4e38f;
    for (int e = 0; e < En; ++e) if (e != e0 && acc[e] > v1) { v1 = acc[e]; e1 = e; }
    const float q  = __expf(v1 - v0);
    const float q0 = 1.f / (1.f + q);
    const float q1 = q * q0;
    topk_e[t * 2] = e0; topk_e[t * 2 + 1] = e1;
    topk_p[t * 2] = q0; topk_p[t * 2 + 1] = q1;
  }
}

// ---------------- reduce+scatter (single block, LDS atomics only) ----------------
__global__ __launch_bounds__(256) void reduce_scatter_kernel(
    const int* __restrict__ topk_e, const float* __restrict__ topk_p,
    const float* __restrict__ gate_p,
    int* __restrict__ counts, int* __restrict__ offs,
    int* __restrict__ pair_token, int* __restrict__ slot_of,
    float* __restrict__ out_scalar)
{
  __shared__ int cnt_s[En];
  __shared__ int run_s[En];
  __shared__ float red[256 * En];
  const int tid = threadIdx.x;
  if (tid < En) cnt_s[tid] = 0;
  __syncthreads();
  for (int i = tid; i < Tn * 2; i += 256) atomicAdd(&cnt_s[topk_e[i]], 1);
  __syncthreads();
  if (tid == 0) {
    int o = 0;
    for (int e = 0; e < En; ++e) {
      offs[e] = o; run_s[e] = o; counts[e] = cnt_s[e]; o += cnt_s[e];
    }
  }
  __syncthreads();
  for (int i = tid; i < Tn * 2; i += 256) {
    const int e = topk_e[i];
    const int slot = atomicAdd(&run_s[e], 1);
    pair_token[slot] = i >> 1;
    slot_of[i] = slot;
  }
  float p8[En];
#pragma unroll
  for (int e = 0; e < En; ++e) p8[e] = 0.f;
  for (int t = tid; t < Tn; t += 256)
#pragma unroll
    for (int e = 0; e < En; ++e) p8[e] += gate_p[t * En + e];
#pragma unroll
  for (int e = 0; e < En; ++e) red[tid * En + e] = p8[e];
  __syncthreads();
  for (int s = 128; s > 0; s >>= 1) {
    if (tid < s)
#pragma unroll
      for (int e = 0; e < En; ++e) red[tid * En + e] += red[(tid + s) * En + e];
    __syncthreads();
  }
  if (tid == 0) {
    double mp[En]; double sum = 0.0;
    for (int e = 0; e < En; ++e) { mp[e] = (double)red[e] / (double)Tn; sum += mp[e]; }
    const double mean = sum / En;
    double var = 0.0;
    for (int e = 0; e < En; ++e) { const double d = mp[e] - mean; var += d * d; }
    var /= (En - 1);
    const double denom = mean + 1e-10;
    *out_scalar = (float)(0.01 * var / (denom * denom));
  }
}

// ---------------- w1/w3 fp32 [E][Hh][Dm] -> bf16 [E][HP][Dm], pad rows zero ----------------
__global__ __launch_bounds__(256) void cvt_w13_kernel(
    const float* __restrict__ w1, const float* __restrict__ w3,
    unsigned short* __restrict__ w1b, unsigned short* __restrict__ w3b)
{
  const float* src = blockIdx.y ? w3 : w1;
  unsigned short* dst = blockIdx.y ? w3b : w1b;
  const unsigned i = ((unsigned)blockIdx.x * 256u + threadIdx.x) * 8u;
  const unsigned per_e = (unsigned)HP * Dm;
  const unsigned e = i / per_e;
  const unsigned r = i % per_e;
  const unsigned row = r / Dm, col = r % Dm;
  uint4 v;
  if (row < Hh) {
    const float* s = src + (size_t)e * Hh * Dm + (size_t)row * Dm + col;
    float f[8];
    *(float4*)(f)     = *(const float4*)(s);
    *(float4*)(f + 4) = *(const float4*)(s + 4);
    v = pack8(f);
  } else {
    v = (uint4){0, 0, 0, 0};
  }
  *(uint4*)(dst + i) = v;
}

// ---------------- w2 fp32 [E][Dm][Hh] -> bf16 [E][Dm][HP], pad cols zero ----------------
__global__ __launch_bounds__(256) void cvt_w2_kernel(const float* __restrict__ w2,
                                                     unsigned short* __restrict__ w2b)
{
  const unsigned i = ((unsigned)blockIdx.x * 256u + threadIdx.x) * 8u;
  const unsigned per_e = (unsigned)Dm * HP;
  const unsigned e = i / per_e;
  const unsigned r = i % per_e;
  const unsigned row = r / HP, col = r % HP;
  const float* s = w2 + (size_t)e * Dm * Hh + (size_t)row * Hh + col;
  float f[8];
#pragma unroll
  for (int k = 0; k < 8; ++k) f[k] = (col + k < Hh) ? s[k] : 0.f;
  *(uint4*)(w2b + i) = pack8(f);
}

// ---------------- GEMM1: h = silu(x w1^T) * (x w3^T), routed ----------------
// 128x128 tile, BK=32, dbuf + counted vmcnt + LDS XOR swizzle. (round-16 proven)
__global__ __launch_bounds__(256, 2) void gemm1_kernel(
    const unsigned short* __restrict__ xb,
    const unsigned short* __restrict__ w1b, const unsigned short* __restrict__ w3b,
    const int* __restrict__ counts, const int* __restrict__ offs,
    const int* __restrict__ pair_token,
    unsigned short* __restrict__ h)
{
  const int bid = blockIdx.x;
  const int logical = (bid & 7) * 344 + (bid >> 3);
  const int z  = logical & 7;
  const int pe = logical >> 3;
  const int e  = pe & 7;
  const int jp = pe >> 3;

  const int cnt = counts[e];
  if (cnt <= 0) return;
  const int base = offs[e];
  const int j0 = jp * 128;
  const int tid = threadIdx.x;
  const int l = tid & 63;
  const int wid = tid >> 6;
  const int wr = wid >> 1, wc = wid & 1;

  __shared__ unsigned short As[2][128 * 32];
  __shared__ unsigned short B1[2][128 * 32];
  __shared__ unsigned short B3[2][128 * 32];

  const int r0 = tid >> 2;
  const int r1 = 64 + (tid >> 2);
  const int c0 = (((tid & 3) ^ ((tid >> 3) & 3))) * 8;   // swizzled col8
  const int wb0 = wid * 512;
  const int wb1 = 2048 + wid * 512;

  const unsigned short* b1r0 = w1b + ((size_t)e * HP + j0 + r0) * Dm + c0;
  const unsigned short* b1r1 = w1b + ((size_t)e * HP + j0 + r1) * Dm + c0;
  const unsigned short* b3r0 = w3b + ((size_t)e * HP + j0 + r0) * Dm + c0;
  const unsigned short* b3r1 = w3b + ((size_t)e * HP + j0 + r1) * Dm + c0;

  const int lr = l & 15;
  const int sq = (((l >> 4) ^ ((lr >> 1) & 3))) * 8;

#define STAGE1(b, kk) do { \
    gl16(a0 + (kk), &As[b][wb0]);   gl16(a1 + (kk), &As[b][wb1]); \
    gl16(b1r0 + (kk), &B1[b][wb0]); gl16(b1r1 + (kk), &B1[b][wb1]); \
    gl16(b3r0 + (kk), &B3[b][wb0]); gl16(b3r1 + (kk), &B3[b][wb1]); \
  } while (0)

#define COMPUTE1(b) do { \
    bf16x8 av[4], b1v[4], b3v[4]; \
    _Pragma("unroll") \
    for (int m = 0; m < 4; ++m) \
      av[m] = *(const bf16x8*)(&As[b][(wr * 64 + m * 16 + lr) * 32 + sq]); \
    _Pragma("unroll") \
    for (int n = 0; n < 4; ++n) { \
      b1v[n] = *(const bf16x8*)(&B1[b][(wc * 64 + n * 16 + lr) * 32 + sq]); \
      b3v[n] = *(const bf16x8*)(&B3[b][(wc * 64 + n * 16 + lr) * 32 + sq]); \
    } \
    _Pragma("unroll") \
    for (int m = 0; m < 4; ++m) \
      _Pragma("unroll") \
      for (int n = 0; n < 4; ++n) { \
        acc1[m][n] = __builtin_amdgcn_mfma_f32_16x16x32_bf16(av[m], b1v[n], acc1[m][n], 0, 0, 0); \
        acc3[m][n] = __builtin_amdgcn_mfma_f32_16x16x32_bf16(av[m], b3v[n], acc3[m][n], 0, 0, 0); \
      } \
  } while (0)

  for (int mt = z; mt * 128 < cnt; mt += 8) {
    const int row0 = mt * 128;
    int s0 = row0 + r0; if (s0 >= cnt) s0 = cnt - 1;
    int s1 = row0 + r1; if (s1 >= cnt) s1 = cnt - 1;
    const unsigned short* a0 = xb + (size_t)pair_token[base + s0] * Dm + c0;
    const unsigned short* a1 = xb + (size_t)pair_token[base + s1] * Dm + c0;

    f32x4 acc1[4][4], acc3[4][4];
#pragma unroll
    for (int m = 0; m < 4; ++m)
#pragma unroll
      for (int n = 0; n < 4; ++n) {
        acc1[m][n] = (f32x4){0.f, 0.f, 0.f, 0.f};
        acc3[m][n] = (f32x4){0.f, 0.f, 0.f, 0.f};
      }

    STAGE1(0, 0);
    int cur = 0;
    for (int kk = 0; kk < Dm - 32; kk += 32) {
      STAGE1(cur ^ 1, kk + 32);
      WAIT6_BAR();
      COMPUTE1(cur);
      LGK0_BAR();
      cur ^= 1;
    }
    WAIT0_BAR();
    COMPUTE1(cur);
    LGK0_BAR();

#pragma unroll
    for (int m = 0; m < 4; ++m) {
      const int rb = wr * 64 + m * 16 + ((l >> 4) << 2);
#pragma unroll
      for (int i = 0; i < 4; ++i) {
        const int sl2 = row0 + rb + i;
        if (sl2 < cnt) {
          unsigned short* hrow = h + (size_t)(base + sl2) * HP + j0 + wc * 64 + lr;
#pragma unroll
          for (int n = 0; n < 4; ++n) {
            const float aa = acc1[m][n][i];
            const float g = aa / (1.f + __expf(-aa));
            hrow[n * 16] = f2bf(g * acc3[m][n][i]);
          }
        }
      }
    }
  }
#undef STAGE1
#undef COMPUTE1
}

// ---------------- GEMM2: y[slot] = h[slot] w2^T (NO atomics, plain stores) ----------------
// 128x128 tile, BK=64, dbuf + counted vmcnt + 3-bit XOR swizzle.
__global__ __launch_bounds__(256, 2) void gemm2_kernel(
    const unsigned short* __restrict__ h, const unsigned short* __restrict__ w2b,
    const int* __restrict__ counts, const int* __restrict__ offs,
    float* __restrict__ y)
{
  const int bid = blockIdx.x;
  const int logical = (bid & 7) * 128 + (bid >> 3);
  const int z  = logical & 7;
  const int pe = logical >> 3;
  const int e  = pe & 7;
  const int dp = pe >> 3;

  const int cnt = counts[e];
  if (cnt <= 0) return;
  const int base = offs[e];
  const int d0 = dp * 128;
  const int tid = threadIdx.x;
  const int l = tid & 63;
  const int wid = tid >> 6;
  const int wr = wid >> 1, wc = wid & 1;

  __shared__ unsigned short Ah[2][128 * 64];
  __shared__ unsigned short Bs[2][128 * 64];

  const int r0 = tid >> 3;
  const int c0 = (((tid & 7) ^ ((tid >> 3) & 7))) * 8;

  const unsigned short* br0 = w2b + ((size_t)e * Dm + d0 + r0)      * HP + c0;
  const unsigned short* br1 = w2b + ((size_t)e * Dm + d0 + r0 + 32) * HP + c0;
  const unsigned short* br2 = w2b + ((size_t)e * Dm + d0 + r0 + 64) * HP + c0;
  const unsigned short* br3 = w2b + ((size_t)e * Dm + d0 + r0 + 96) * HP + c0;

  const int wbA0 = (0 * 256 + wid * 64) * 8;
  const int wbA1 = (1 * 256 + wid * 64) * 8;
  const int wbA2 = (2 * 256 + wid * 64) * 8;
  const int wbA3 = (3 * 256 + wid * 64) * 8;

  const int lr = l & 15;
  const int sq0 = (((0 * 4 + (l >> 4)) ^ (lr & 7))) * 8;
  const int sq1 = (((1 * 4 + (l >> 4)) ^ (lr & 7))) * 8;

#define STAGE2(b, kk) do { \
    gl16(a0 + (kk), &Ah[b][wbA0]); gl16(a1 + (kk), &Ah[b][wbA1]); \
    gl16(a2 + (kk), &Ah[b][wbA2]); gl16(a3 + (kk), &Ah[b][wbA3]); \
    gl16(br0 + (kk), &Bs[b][wbA0]); gl16(br1 + (kk), &Bs[b][wbA1]); \
    gl16(br2 + (kk), &Bs[b][wbA2]); gl16(br3 + (kk), &Bs[b][wbA3]); \
  } while (0)

#define COMPUTE2(b) do { \
    bf16x8 av[4], bv[4]; \
    _Pragma("unroll") \
    for (int m = 0; m < 4; ++m) \
      av[m] = *(const bf16x8*)(&Ah[b][(wr * 64 + m * 16 + lr) * 64 + sq0]); \
    _Pragma("unroll") \
    for (int n = 0; n < 4; ++n) \
      bv[n] = *(const bf16x8*)(&Bs[b][(wc * 64 + n * 16 + lr) * 64 + sq0]); \
    _Pragma("unroll") \
    for (int m = 0; m < 4; ++m) \
      _Pragma("unroll") \
      for (int n = 0; n < 4; ++n) \
        acc[m][n] = __builtin_amdgcn_mfma_f32_16x16x32_bf16(av[m], bv[n], acc[m][n], 0, 0, 0); \
    _Pragma("unroll") \
    for (int m = 0; m < 4; ++m) \
      av[m] = *(const bf16x8*)(&Ah[b][(wr * 64 + m * 16 + lr) * 64 + sq1]); \
    _Pragma("unroll") \
    for (int n = 0; n < 4; ++n) \
      bv[n] = *(const bf16x8*)(&Bs[b][(wc * 64 + n * 16 + lr) * 64 + sq1]); \
    _Pragma("unroll") \
    for (int m = 0; m < 4; ++m) \
      _Pragma("unroll") \
      for (int n = 0; n < 4; ++n) \
        acc[m][n] = __builtin_amdgcn_mfma_f32_16x16x32_bf16(av[m], bv[n], acc[m][n], 0, 0, 0); \
  } while (0)

  for (int mt = z; mt * 128 < cnt; mt += 8) {
    const int row0 = mt * 128;
    int s0 = row0 + r0;      if (s0 >= cnt) s0 = cnt - 1;
    int s1 = row0 + r0 + 32; if (s1 >= cnt) s1 = cnt - 1;
    int s2 = row0 + r0 + 64; if (s2 >= cnt) s2 = cnt - 1;
    int s3 = row0 + r0 + 96; if (s3 >= cnt) s3 = cnt - 1;
    const unsigned short* a0 = h + (size_t)(base + s0) * HP + c0;
    const unsigned short* a1 = h + (size_t)(base + s1) * HP + c0;
    const unsigned short* a2 = h + (size_t)(base + s2) * HP + c0;
    const unsigned short* a3 = h + (size_t)(base + s3) * HP + c0;

    f32x4 acc[4][4];
#pragma unroll
    for (int m = 0; m < 4; ++m)
#pragma unroll
      for (int n = 0; n < 4; ++n) acc[m][n] = (f32x4){0.f, 0.f, 0.f, 0.f};

    STAGE2(0, 0);
    int cur = 0;
    for (int kk = 0; kk < HP - 64; kk += 64) {
      STAGE2(cur ^ 1, kk + 64);
      WAIT8_BAR();
      COMPUTE2(cur);
      LGK0_BAR();
      cur ^= 1;
    }
    WAIT0_BAR();
    COMPUTE2(cur);
    LGK0_BAR();

#pragma unroll
    for (int m = 0; m < 4; ++m) {
      const int rb = row0 + wr * 64 + m * 16 + ((l >> 4) << 2);
#pragma unroll
      for (int i = 0; i < 4; ++i) {
        const int sl2 = rb + i;
        if (sl2 < cnt) {
          float* yrow = y + (size_t)(base + sl2) * Dm + d0 + wc * 64 + lr;
#pragma unroll
          for (int n = 0; n < 4; ++n)
            yrow[n * 16] = acc[m][n][i];
        }
      }
    }
  }
#undef STAGE2
#undef COMPUTE2
}

// ---------------- combine: out[t] = w0*y[slot0] + w1*y[slot1] ----------------
__global__ __launch_bounds__(256) void combine_kernel(
    const float* __restrict__ y, const int* __restrict__ slot_of,
    const float* __restrict__ topk_p, float* __restrict__ out)
{
  const int t = blockIdx.x;
  const int s0 = slot_of[t * 2], s1 = slot_of[t * 2 + 1];
  const float w0 = topk_p[t * 2], w1 = topk_p[t * 2 + 1];
  const float* y0 = y + (size_t)s0 * Dm;
  const float* y1 = y + (size_t)s1 * Dm;
  float* o = out + (size_t)t * Dm;
  const int c = threadIdx.x * 8;
  float4 a0 = *(const float4*)(y0 + c);
  float4 a1 = *(const float4*)(y0 + c + 4);
  float4 b0 = *(const float4*)(y1 + c);
  float4 b1 = *(const float4*)(y1 + c + 4);
  float4 r0, r1;
  r0.x = w0 * a0.x + w1 * b0.x; r0.y = w0 * a0.y + w1 * b0.y;
  r0.z = w0 * a0.z + w1 * b0.z; r0.w = w0 * a0.w + w1 * b0.w;
  r1.x = w0 * a1.x + w1 * b1.x; r1.y = w0 * a1.y + w1 * b1.y;
  r1.z = w0 * a1.z + w1 * b1.z; r1.w = w0 * a1.w + w1 * b1.w;
  *(float4*)(o + c) = r0;
  *(float4*)(o + c + 4) = r1;
}

extern "C" void kernel_launch(void* const* d_in, const int* in_sizes, int n_in,
                              void* d_out, int out_size, void* d_ws, size_t ws_size,
                              hipStream_t stream) {
  const float* x  = (const float*)d_in[0];
  const float* wg = (const float*)d_in[1];
  const float* w1 = (const float*)d_in[2];
  const float* w2 = (const float*)d_in[3];
  const float* w3 = (const float*)d_in[4];
  float* out = (float*)d_out;

  char* ws = (char*)d_ws;
  int*    counts     = (int*)(ws + 64);
  int*    offs       = (int*)(ws + 128);
  int*    topk_e     = (int*)(ws + 1024);
  float*  topk_p     = (float*)(ws + 40960);
  int*    pair_token = (int*)(ws + 81920);
  float*  gate_p     = (float*)(ws + 163840);
  int*    slot_of    = (int*)(ws + 307200);
  const size_t MB = 1u << 20;
  unsigned short* xb  = (unsigned short*)(ws + 1 * MB);    // 16 MiB
  unsigned short* h   = (unsigned short*)(ws + 17 * MB);   // 86 MiB
  unsigned short* w1b = (unsigned short*)(ws + 104 * MB);  // 172 MiB
  unsigned short* w3b = (unsigned short*)(ws + 276 * MB);  // 172 MiB
  unsigned short* w2b = (unsigned short*)(ws + 448 * MB);  // 172 MiB -> ends 620 MiB
  // y reuses w1b's region (stream-ordered: gemm1 done with w1b before gemm2).
  float* y = (float*)(ws + 104 * MB);                      // 64 MiB

  gating_kernel  <<<Tn, 64, 0, stream>>>(x, wg, gate_p, topk_e, topk_p, xb);
  reduce_scatter_kernel<<<1, 256, 0, stream>>>(topk_e, topk_p, gate_p, counts, offs,
                                               pair_token, slot_of, out + (size_t)Tn * Dm);
  cvt_w13_kernel <<<dim3(En * HP * Dm / 8 / 256, 2), 256, 0, stream>>>(w1, w3, w1b, w3b);
  cvt_w2_kernel  <<<En * Dm * HP / 8 / 256, 256, 0, stream>>>(w2, w2b);
  gemm1_kernel   <<<43 * En * 8, 256, 0, stream>>>(xb, w1b, w3b, counts, offs, pair_token, h);
  gemm2_kernel   <<<(Dm / 128) * En * 8, 256, 0, stream>>>(h, w2b, counts, offs, y);
  combine_kernel <<<Tn, 256, 0, stream>>>(y, slot_of, topk_p, out);
}